// Round 1
// baseline (335.387 us; speedup 1.0000x reference)
//
#include <hip/hip_runtime.h>

// DecayModel: out[b,i,h] = (fwd[i] + bwd[i]) / norm[i]
//   fwd[i] = sum_{k<=i} 0.5^{i-k} x[k]   (causal IIR, decay 0.5)
//   bwd[i] = sum_{k>=i} 0.5^{k-i} x[k]   (anticausal IIR)
//   norm[i] = 4 - 2^{-i} - 2^{-(S-1-i)}
//
// Strategy: decay 0.5 => impulse response < 1.6e-5 beyond lag 16, so the
// global scan is computed as a tiled recurrence with K=16 halo warm-up.
// Each thread owns one (b,h) column for a T=64 s-tile; forward values are
// held in registers (fully unrolled), then the backward pass combines.
// Input (128 MB) fits in 256 MB Infinity Cache => halo/second-pass re-reads
// are LLC hits; HBM traffic ~= compulsory 256 MB => ~41 us roofline.

constexpr int B = 16;
constexpr int S = 2048;
constexpr int H = 1024;
constexpr int T = 64;    // s-tile length per thread (fwdv in registers)
constexpr int K = 16;    // halo taps: 0.5^16 = 1.53e-5, way below threshold
constexpr int BLOCK = 256;
constexpr float DECAY = 0.5f;

__global__ __launch_bounds__(BLOCK, 2) void decay_kernel(
    const float* __restrict__ x, float* __restrict__ out) {
    const int sTiles = S / T;        // 32
    const int hChunks = H / BLOCK;   // 4

    int bid = blockIdx.x;
    int tile = bid % sTiles;
    int tmp = bid / sTiles;
    int hc = tmp % hChunks;
    int b = tmp / hChunks;

    const int h = hc * BLOCK + threadIdx.x;
    const int s0 = tile * T;

    const size_t colBase = (size_t)b * S * H + h;  // element [b, 0, h]
    const float* xp = x + colBase;                 // xp[s*H] = x[b,s,h]
    float* op = out + colBase;

    // ---- forward pass: halo warm-up then tile, storing fwd values ----
    float acc = 0.0f;
    {
        int lo = s0 - K;
        if (lo < 0) lo = 0;
        for (int s = lo; s < s0; ++s)
            acc = fmaf(DECAY, acc, xp[(size_t)s * H]);
    }
    float fwdv[T];
#pragma unroll
    for (int t = 0; t < T; ++t) {
        acc = fmaf(DECAY, acc, xp[(size_t)(s0 + t) * H]);
        fwdv[t] = acc;
    }

    // ---- backward pass: right halo warm-up, then combine ----
    float acc2 = 0.0f;
    {
        int hi = s0 + T - 1 + K;
        if (hi > S - 1) hi = S - 1;
        for (int s = hi; s >= s0 + T; --s)
            acc2 = fmaf(DECAY, acc2, xp[(size_t)s * H]);
    }
#pragma unroll
    for (int t = T - 1; t >= 0; --t) {
        const int i = s0 + t;
        acc2 = fmaf(DECAY, acc2, xp[(size_t)i * H]);
        // norm[i] = 4 - 2^{-i} - 2^{-(S-1-i)}; exp2f underflows to 0 for
        // large args, which is exact here.
        float norm = 4.0f - exp2f((float)(-i)) - exp2f((float)(i - (S - 1)));
        op[(size_t)i * H] = (fwdv[t] + acc2) / norm;
    }
}

extern "C" void kernel_launch(void* const* d_in, const int* in_sizes, int n_in,
                              void* d_out, int out_size, void* d_ws,
                              size_t ws_size, hipStream_t stream) {
    const float* x = (const float*)d_in[0];
    float* out = (float*)d_out;
    const int blocks = B * (H / BLOCK) * (S / T);  // 16*4*32 = 2048
    decay_kernel<<<blocks, BLOCK, 0, stream>>>(x, out);
}

// Round 2
// 245.713 us; speedup vs baseline: 1.3650x; 1.3650x over previous
//
#include <hip/hip_runtime.h>

// DecayModel: out[b,i,h] = (fwd[i] + bwd[i]) / norm[i]
//   fwd[i] = sum_{k<=i} 0.5^{i-k} x[k]   (causal IIR, decay 0.5)
//   bwd[i] = sum_{k>=i} 0.5^{k-i} x[k]   (anticausal IIR)
//   norm[i] = 4 - 2^{-i} - 2^{-(S-1-i)}  (== 4 exactly for interior i)
//
// R1 -> R2: kernel was latency-bound (1.5 TB/s, VALUBusy 14%, occ 21%).
//  - float4 loads (thread owns 4 h-columns): 1 KB/wave-instruction.
//  - backward pass recovers x[t] = fwd[t] - 0.5*fwd[t-1] from registers:
//    tile is read from global ONCE (only right-halo K loads added).
//  - K=12 halo (0.5^12 * 6sigma ~ 1.5e-3 << 6.4e-2 threshold).
//  - norm hoisted: interior tiles use rn = 0.25 exactly; only the first
//    and last s-tile run exp2f/div.

constexpr int B = 16;
constexpr int S = 2048;
constexpr int H = 1024;
constexpr int T = 32;    // s-steps per tile; fwd[T] float4 in registers
constexpr int K = 12;    // halo taps
constexpr int BLOCK = 256;
constexpr int HV = H / 4;  // row length in float4

__device__ __forceinline__ float4 fma4(float a, const float4& p, const float4& v) {
    float4 r;
    r.x = fmaf(a, p.x, v.x);
    r.y = fmaf(a, p.y, v.y);
    r.z = fmaf(a, p.z, v.z);
    r.w = fmaf(a, p.w, v.w);
    return r;
}

__global__ __launch_bounds__(BLOCK, 3) void decay_kernel(
    const float4* __restrict__ x, float4* __restrict__ out) {
    const int tile = blockIdx.x;   // 0..S/T-1
    const int b = blockIdx.y;      // 0..B-1
    const int s0 = tile * T;

    const size_t rowBase = (size_t)b * S * HV + threadIdx.x;  // float4 units
    const float4* xp = x + rowBase;   // xp[s*HV] = x[b, s, 4*tid .. 4*tid+3]
    float4* op = out + rowBase;

    // ---- left halo warm-up ----
    float4 acc = make_float4(0.f, 0.f, 0.f, 0.f);
    {
        int lo = s0 - K;
        if (lo < 0) lo = 0;
        for (int s = lo; s < s0; ++s)
            acc = fma4(0.5f, acc, xp[(size_t)s * HV]);
    }
    const float4 fwdm1 = acc;  // fwd value just before the tile

    // ---- forward pass over tile (single global read of the tile) ----
    float4 fwd[T];
#pragma unroll
    for (int t = 0; t < T; ++t) {
        acc = fma4(0.5f, acc, xp[(size_t)(s0 + t) * HV]);
        fwd[t] = acc;
    }

    // ---- right halo warm-up for backward pass ----
    float4 acc2 = make_float4(0.f, 0.f, 0.f, 0.f);
    {
        int hi = s0 + T - 1 + K;
        if (hi > S - 1) hi = S - 1;
        for (int s = hi; s >= s0 + T; --s)
            acc2 = fma4(0.5f, acc2, xp[(size_t)s * HV]);
    }

    // ---- backward pass: x recovered from fwd registers; no tile re-read ----
    const bool interior = (s0 >= 32) && (s0 <= S - T - 32);
#pragma unroll
    for (int t = T - 1; t >= 0; --t) {
        const float4 prev = (t > 0) ? fwd[t - 1] : fwdm1;
        // x[t] = fwd[t] - 0.5*prev
        float4 xt;
        xt.x = fmaf(-0.5f, prev.x, fwd[t].x);
        xt.y = fmaf(-0.5f, prev.y, fwd[t].y);
        xt.z = fmaf(-0.5f, prev.z, fwd[t].z);
        xt.w = fmaf(-0.5f, prev.w, fwd[t].w);
        acc2 = fma4(0.5f, acc2, xt);

        float rn;
        if (interior) {
            rn = 0.25f;  // norm == 4 exactly (2^-i underflows/negligible)
        } else {
            const int i = s0 + t;
            const float norm =
                4.0f - exp2f((float)(-i)) - exp2f((float)(i - (S - 1)));
            rn = 1.0f / norm;
        }
        float4 o;
        o.x = (fwd[t].x + acc2.x) * rn;
        o.y = (fwd[t].y + acc2.y) * rn;
        o.z = (fwd[t].z + acc2.z) * rn;
        o.w = (fwd[t].w + acc2.w) * rn;
        op[(size_t)(s0 + t) * HV] = o;
    }
}

extern "C" void kernel_launch(void* const* d_in, const int* in_sizes, int n_in,
                              void* d_out, int out_size, void* d_ws,
                              size_t ws_size, hipStream_t stream) {
    const float4* x = (const float4*)d_in[0];
    float4* out = (float4*)d_out;
    dim3 grid(S / T, B);  // 64 x 16 = 1024 blocks
    decay_kernel<<<grid, BLOCK, 0, stream>>>(x, out);
}